// Round 3
// baseline (520.484 us; speedup 1.0000x reference)
//
#include <hip/hip_runtime.h>
#include <hip/hip_bf16.h>

#define Bb   4
#define Hh   16
#define Ss   2048
#define Dd   128
#define QBLK 128
#define KVB  64
#define NW   4

typedef __attribute__((ext_vector_type(8))) short bf16x8;
typedef __attribute__((ext_vector_type(4))) float f32x4;
typedef __attribute__((ext_vector_type(4))) float fvec4;
typedef __attribute__((ext_vector_type(2))) unsigned u32x2;

__device__ __forceinline__ unsigned pk2(float a, float b) {
    __hip_bfloat162 h = __float22bfloat162_rn(make_float2(a, b));
    unsigned u; __builtin_memcpy(&u, &h, 4); return u;
}

// ---------- kernel 1: partial V sums (512 blocks: bh x 8 chunks of 256 rows) ----------
__global__ __launch_bounds__(256) void vpart_kernel(const float* __restrict__ V,
                                                    float* __restrict__ part) {
    int blk = blockIdx.x, bh = blk >> 3, ch = blk & 7;
    int tid = threadIdx.x, d4 = tid & 31, rg = tid >> 5;
    const fvec4* p = (const fvec4*)(V + ((size_t)bh * Ss + ch * 256) * Dd) + d4;
    fvec4 s = {0.f, 0.f, 0.f, 0.f};
    for (int rr = 0; rr < 32; ++rr) s += p[(size_t)(rg * 32 + rr) * 32];
    __shared__ fvec4 red[256];
    red[tid] = s;
    __syncthreads();
    for (int off = 128; off >= 32; off >>= 1) {
        if (tid < off) red[tid] += red[tid + off];
        __syncthreads();
    }
    if (tid < 32) ((fvec4*)(part + (size_t)blk * Dd))[tid] = red[tid];
}

// ---------- kernel 2: combine partials -> vmean ----------
__global__ __launch_bounds__(128) void vcomb_kernel(const float* __restrict__ part,
                                                    float* __restrict__ vm) {
    int bh = blockIdx.x, d = threadIdx.x;
    float s = 0.f;
    #pragma unroll
    for (int c = 0; c < 8; ++c) s += part[(size_t)(bh * 8 + c) * Dd + d];
    vm[bh * Dd + d] = s * (1.0f / 2048.0f);
}

// ---------- kernel 3: flash attention, async-split staging, 3 blocks/CU ----------
__global__ __launch_bounds__(256, 3) void attn_kernel(
    const float* __restrict__ Qg, const float* __restrict__ Kg,
    const float* __restrict__ Vg, const int* __restrict__ slen,
    const float* __restrict__ vmean, float* __restrict__ Og)
{
    __shared__ __align__(16) short Ks[KVB * Dd];       // 16KB
    __shared__ __align__(16) short Vt[Dd * KVB];       // 16KB
    __shared__ __align__(16) short Ps[NW * 32 * KVB];  // 16KB

    const int bid = blockIdx.x;
    const int qslot = bid >> 6, r = bid & 63;
    const int qt = 15 - qslot;                         // longest q-tiles launch first
    // batch spans all 8 XCDs; (b,h)'s 16 q-tiles share bid%8 -> same XCD (L2 reuse)
    const int b  = (r >> 3) & 3;
    const int h  = (r & 7) | ((r >> 5) << 3);
    const int bh = b * 16 + h;
    const int len = slen[b];
    const int q0 = qt * QBLK;
    const int tid = threadIdx.x;

    // fully-invalid block: each row = mean of V over all S (uniform softmax)
    if (q0 >= len) {
        const fvec4* vm4 = (const fvec4*)(vmean + bh * Dd);
        fvec4 val = vm4[tid & 31];
        float* ob = Og + ((size_t)bh * Ss + q0) * Dd;
        int r0 = tid >> 5;
        #pragma unroll
        for (int i = 0; i < 16; ++i)
            ((fvec4*)(ob + (size_t)(r0 + 8 * i) * Dd))[tid & 31] = val;
        return;
    }

    const int w = tid >> 6, lane = tid & 63;
    const int g = lane >> 4, qc = lane & 15;
    const int qw0 = q0 + w * 32;
    const bool wave_active = (qw0 < len);

    const float* Kbase = Kg + (size_t)bh * Ss * Dd;
    const float* Vbase = Vg + (size_t)bh * Ss * Dd;

    const int kv_end   = min(q0 + QBLK, len);
    const int kv_end_w = min(qw0 + 32, kv_end);
    const int nt = (kv_end + KVB - 1) >> 6;

    fvec4 rK[8], rV[8];

    #define ISSUE(tile_)  do {                                                         \
        const fvec4* sk_ = (const fvec4*)(Kbase + (size_t)(tile_) * KVB * Dd);         \
        _Pragma("unroll")                                                              \
        for (int i_ = 0; i_ < 8; ++i_)                                                 \
            rK[i_] = sk_[(size_t)((tid >> 5) + 8 * i_) * 32 + (tid & 31)];             \
        const fvec4* sv_ = (const fvec4*)(Vbase + (size_t)(tile_) * KVB * Dd);         \
        _Pragma("unroll")                                                              \
        for (int i_ = 0; i_ < 2; ++i_) {                                               \
            int kt4_ = (tid >> 5) + 8 * i_;                                            \
            _Pragma("unroll")                                                          \
            for (int jj_ = 0; jj_ < 4; ++jj_)                                          \
                rV[i_ * 4 + jj_] = sv_[(size_t)(kt4_ * 4 + jj_) * 32 + (tid & 31)];    \
        }                                                                              \
    } while (0)

    #define WRITE_K() do {                                                             \
        _Pragma("unroll")                                                              \
        for (int i_ = 0; i_ < 8; ++i_) {                                               \
            int kr_ = (tid >> 5) + 8 * i_, d4_ = tid & 31;                             \
            u32x2 pr_;                                                                 \
            pr_[0] = pk2(rK[i_][0], rK[i_][1]);                                        \
            pr_[1] = pk2(rK[i_][2], rK[i_][3]);                                        \
            int bo_ = (kr_ * 256 + d4_ * 8) ^ ((kr_ & 7) << 4);                        \
            *(u32x2*)((char*)Ks + bo_) = pr_;                                          \
        }                                                                              \
    } while (0)

    #define WRITE_V() do {                                                             \
        _Pragma("unroll")                                                              \
        for (int i_ = 0; i_ < 2; ++i_) {                                               \
            int dt4_ = tid & 31, kt4_ = (tid >> 5) + 8 * i_;                           \
            int k0_ = kt4_ * 4, d0_ = dt4_ * 4;                                        \
            _Pragma("unroll")                                                          \
            for (int jj_ = 0; jj_ < 4; ++jj_) {                                        \
                int d_ = d0_ + jj_;                                                    \
                u32x2 pr_;                                                             \
                pr_[0] = pk2(rV[i_ * 4 + 0][jj_], rV[i_ * 4 + 1][jj_]);                \
                pr_[1] = pk2(rV[i_ * 4 + 2][jj_], rV[i_ * 4 + 3][jj_]);                \
                int bo_ = (d_ * 128 + k0_ * 2) ^ ((d_ & 15) << 3);                     \
                *(u32x2*)((char*)Vt + bo_) = pr_;                                      \
            }                                                                          \
        }                                                                              \
    } while (0)

    // prologue: stage tile 0; Q-fragment load overlaps the staging-load latency
    ISSUE(0);

    const float SC = 0.12752870368768582f;  // log2(e)/sqrt(128)
    bf16x8 qf[2][4];
    #pragma unroll
    for (int t2 = 0; t2 < 2; ++t2) {
        const float* qrow = Qg + ((size_t)bh * Ss + (qw0 + 16 * t2 + qc)) * Dd;
        #pragma unroll
        for (int kc = 0; kc < 4; ++kc) {
            const fvec4* p = (const fvec4*)(qrow + kc * 32 + g * 8);
            fvec4 a = p[0], bv = p[1];
            unsigned* fu = (unsigned*)&qf[t2][kc];
            fu[0] = pk2(a[0] * SC, a[1] * SC);
            fu[1] = pk2(a[2] * SC, a[3] * SC);
            fu[2] = pk2(bv[0] * SC, bv[1] * SC);
            fu[3] = pk2(bv[2] * SC, bv[3] * SC);
        }
    }

    WRITE_K();
    WRITE_V();
    __syncthreads();

    f32x4 o[2][8];
    #pragma unroll
    for (int t2 = 0; t2 < 2; ++t2)
        #pragma unroll
        for (int dt = 0; dt < 8; ++dt) o[t2][dt] = (f32x4){0.f, 0.f, 0.f, 0.f};
    float m_[2]   = {-3e38f, -3e38f};
    float lsum[2] = {0.f, 0.f};

    char* PsB = (char*)Ps + w * 4096;

    for (int t = 0; t < nt; ++t) {
        const int kv0 = t * KVB;
        const bool pre = (t + 1 < nt);
        const bool active = wave_active && (kv0 < kv_end_w);

        if (pre) ISSUE(t + 1);  // next tile's loads fly under this tile's compute

        if (active) {
            f32x4 sa[2][4];
            #pragma unroll
            for (int t2 = 0; t2 < 2; ++t2)
                #pragma unroll
                for (int mt = 0; mt < 4; ++mt) sa[t2][mt] = (f32x4){0.f, 0.f, 0.f, 0.f};
            __builtin_amdgcn_s_setprio(1);
            #pragma unroll
            for (int mt = 0; mt < 4; ++mt) {
                bf16x8 kf[4];
                int row = mt * 16 + qc;
                int swz = (row & 7) << 4;
                #pragma unroll
                for (int kc = 0; kc < 4; ++kc)
                    kf[kc] = *(const bf16x8*)((const char*)Ks + ((row * 256 + kc * 64 + g * 16) ^ swz));
                #pragma unroll
                for (int t2 = 0; t2 < 2; ++t2)
                    #pragma unroll
                    for (int kc = 0; kc < 4; ++kc)
                        sa[t2][mt] = __builtin_amdgcn_mfma_f32_16x16x32_bf16(
                            kf[kc], qf[t2][kc], sa[t2][mt], 0, 0, 0);
            }
            __builtin_amdgcn_s_setprio(0);

            // ---- mask + online softmax with defer-max ----
            #pragma unroll
            for (int t2 = 0; t2 < 2; ++t2) {
                const int qrow = qw0 + 16 * t2 + qc;
                const bool full = (kv0 + KVB - 1) <= (qw0 + 16 * t2);
                if (!full) {
                    #pragma unroll
                    for (int mt = 0; mt < 4; ++mt)
                        #pragma unroll
                        for (int rr = 0; rr < 4; ++rr) {
                            int kk = kv0 + mt * 16 + g * 4 + rr;
                            if (kk > qrow) sa[t2][mt][rr] = -3e38f;
                        }
                }
                float tm = sa[t2][0][0];
                #pragma unroll
                for (int mt = 0; mt < 4; ++mt)
                    #pragma unroll
                    for (int rr = 0; rr < 4; ++rr) tm = fmaxf(tm, sa[t2][mt][rr]);
                tm = fmaxf(tm, __shfl_xor(tm, 16));
                tm = fmaxf(tm, __shfl_xor(tm, 32));
                if (__any(tm > m_[t2] + 8.0f)) {       // defer-max
                    float mnew = fmaxf(m_[t2], tm);
                    float al = exp2f(m_[t2] - mnew);
                    m_[t2] = mnew;
                    lsum[t2] *= al;
                    #pragma unroll
                    for (int rr = 0; rr < 4; ++rr) {
                        float alr = __shfl(al, g * 4 + rr);
                        #pragma unroll
                        for (int dt = 0; dt < 8; ++dt) o[t2][dt][rr] *= alr;
                    }
                }
                float mref = m_[t2];
                float ls = 0.f;
                int prow = t2 * 16 + qc;
                int pswz = (prow & 7) << 4;
                #pragma unroll
                for (int mt = 0; mt < 4; ++mt) {
                    f32x4 p;
                    #pragma unroll
                    for (int rr = 0; rr < 4; ++rr)
                        p[rr] = exp2f(sa[t2][mt][rr] - mref);
                    ls += (p[0] + p[1]) + (p[2] + p[3]);
                    u32x2 pw;
                    pw[0] = pk2(p[0], p[1]);
                    pw[1] = pk2(p[2], p[3]);
                    *(u32x2*)(PsB + ((prow * 128 + mt * 32 + g * 8) ^ pswz)) = pw;
                }
                lsum[t2] += ls;
            }

            // ---- PV ----
            bf16x8 ap[2][2];
            #pragma unroll
            for (int t2 = 0; t2 < 2; ++t2) {
                int prow = t2 * 16 + qc;
                int pswz = (prow & 7) << 4;
                #pragma unroll
                for (int c = 0; c < 2; ++c)
                    ap[t2][c] = *(const bf16x8*)(PsB + ((prow * 128 + c * 64 + g * 16) ^ pswz));
            }
            __builtin_amdgcn_s_setprio(1);
            #pragma unroll
            for (int dt = 0; dt < 8; ++dt) {
                int d = dt * 16 + qc;
                int swz = (d & 15) << 3;
                #pragma unroll
                for (int c = 0; c < 2; ++c) {
                    int base = d * 128 + c * 64 + g * 16;
                    u32x2 lo = *(const u32x2*)((const char*)Vt + (base ^ swz));
                    u32x2 hi = *(const u32x2*)((const char*)Vt + ((base + 8) ^ swz));
                    bf16x8 bfv;
                    unsigned* bu = (unsigned*)&bfv;
                    bu[0] = lo[0]; bu[1] = lo[1]; bu[2] = hi[0]; bu[3] = hi[1];
                    #pragma unroll
                    for (int t2 = 0; t2 < 2; ++t2)
                        o[t2][dt] = __builtin_amdgcn_mfma_f32_16x16x32_bf16(
                            ap[t2][c], bfv, o[t2][dt], 0, 0, 0);
                }
            }
            __builtin_amdgcn_s_setprio(0);
        }

        if (pre) {
            __syncthreads();      // all waves done reading Ks/Vt for tile t
            WRITE_K();
            WRITE_V();
            __syncthreads();      // tile t+1 staged
        }
    }

    // ---- epilogue ----
    float inv_[2][4];
    #pragma unroll
    for (int t2 = 0; t2 < 2; ++t2) {
        float L = lsum[t2];
        L += __shfl_xor(L, 16);
        L += __shfl_xor(L, 32);
        #pragma unroll
        for (int rr = 0; rr < 4; ++rr) {
            float Lr = __shfl(L, g * 4 + rr);
            inv_[t2][rr] = 1.0f / Lr;
        }
    }
    bool needvm = (qw0 + 32 > len);
    float vmv[8];
    #pragma unroll
    for (int dt = 0; dt < 8; ++dt)
        vmv[dt] = needvm ? vmean[bh * Dd + dt * 16 + qc] : 0.f;
    #pragma unroll
    for (int t2 = 0; t2 < 2; ++t2)
        #pragma unroll
        for (int rr = 0; rr < 4; ++rr) {
            int rowg = qw0 + t2 * 16 + g * 4 + rr;
            float* orow = Og + ((size_t)bh * Ss + rowg) * Dd + qc;
            #pragma unroll
            for (int dt = 0; dt < 8; ++dt) {
                float val = o[t2][dt][rr] * inv_[t2][rr];
                if (rowg >= len) val = vmv[dt];
                orow[dt * 16] = val;
            }
        }
}

extern "C" void kernel_launch(void* const* d_in, const int* in_sizes, int n_in,
                              void* d_out, int out_size, void* d_ws, size_t ws_size,
                              hipStream_t stream) {
    const float* q  = (const float*)d_in[0];
    const float* k  = (const float*)d_in[1];
    const float* v  = (const float*)d_in[2];
    const int*   sl = (const int*)d_in[3];
    float* part = (float*)d_ws;                         // 512*128 floats = 256KB
    float* vm   = (float*)d_ws + 512 * Dd;              // 64*128 floats  = 32KB
    float* out  = (float*)d_out;
    vpart_kernel<<<dim3(512), dim3(256), 0, stream>>>(v, part);
    vcomb_kernel<<<dim3(Bb * Hh), dim3(128), 0, stream>>>(part, vm);
    attn_kernel<<<dim3((Ss / QBLK) * Bb * Hh), dim3(256), 0, stream>>>(q, k, v, sl, vm, out);
}

// Round 4
// 136.744 us; speedup vs baseline: 3.8063x; 3.8063x over previous
//
#include <hip/hip_runtime.h>
#include <hip/hip_bf16.h>

#define Bb   4
#define Hh   16
#define Ss   2048
#define Dd   128
#define QBLK 128
#define KVB  64
#define NW   4

typedef __attribute__((ext_vector_type(8))) short bf16x8;
typedef __attribute__((ext_vector_type(4))) float f32x4;
typedef __attribute__((ext_vector_type(4))) float fvec4;
typedef __attribute__((ext_vector_type(2))) unsigned u32x2;
typedef __attribute__((ext_vector_type(4))) unsigned u32x4;

__device__ __forceinline__ unsigned pk2(float a, float b) {
    __hip_bfloat162 h = __float22bfloat162_rn(make_float2(a, b));
    unsigned u; __builtin_memcpy(&u, &h, 4); return u;
}

typedef const __attribute__((address_space(1))) char* gas_t;
typedef __attribute__((address_space(3))) char* las_t;
__device__ __forceinline__ void gld16(const void* g, void* l) {
    __builtin_amdgcn_global_load_lds((gas_t)g, (las_t)l, 16, 0, 0);
}

// ---------- prepass A: K fp32 [bh][s][d] -> bf16 same layout ----------
__global__ __launch_bounds__(256) void cvtk_kernel(const float* __restrict__ K,
                                                   short* __restrict__ Kb) {
    size_t i = ((size_t)blockIdx.x * 256 + threadIdx.x) * 8;
    fvec4 a = ((const fvec4*)(K + i))[0];
    fvec4 b = ((const fvec4*)(K + i))[1];
    u32x4 u;
    u[0] = pk2(a[0], a[1]); u[1] = pk2(a[2], a[3]);
    u[2] = pk2(b[0], b[1]); u[3] = pk2(b[2], b[3]);
    *(u32x4*)(Kb + i) = u;
}

// ---------- prepass B: V fp32 [bh][s][d] -> bf16 transposed [bh][d][s], + partial col sums ----------
__global__ __launch_bounds__(256) void cvtv_kernel(const float* __restrict__ V,
                                                   short* __restrict__ Vt,
                                                   float* __restrict__ part) {
    __shared__ short Lt[128 * 136];
    __shared__ fvec4 red[256];
    const int bh = blockIdx.x >> 4, ch = blockIdx.x & 15;
    const int tid = threadIdx.x;
    const float* src = V + ((size_t)bh * Ss + ch * 128) * Dd;
    const int c4 = tid & 31, s0 = tid >> 5;
    fvec4 acc = {0.f, 0.f, 0.f, 0.f};
    #pragma unroll
    for (int i = 0; i < 16; ++i) {
        int s = s0 + 8 * i;
        fvec4 v = ((const fvec4*)(src + (size_t)s * Dd))[c4];
        acc += v;
        u32x2 p; p[0] = pk2(v[0], v[1]); p[1] = pk2(v[2], v[3]);
        *(u32x2*)&Lt[s * 136 + c4 * 4] = p;
    }
    red[tid] = acc;
    __syncthreads();
    for (int off = 128; off >= 32; off >>= 1) {
        if (tid < off) red[tid] += red[tid + off];
        __syncthreads();
    }
    if (tid < 32) ((fvec4*)(part + (size_t)blockIdx.x * Dd))[tid] = red[tid];
    // transposed write: row d, s-slice
    #pragma unroll
    for (int i = 0; i < 8; ++i) {
        int g2 = tid + 256 * i;
        int d = g2 >> 4, sg = g2 & 15;
        short tmp[8];
        #pragma unroll
        for (int j = 0; j < 8; ++j) tmp[j] = Lt[(sg * 8 + j) * 136 + d];
        u32x4 u; __builtin_memcpy(&u, tmp, 16);
        *(u32x4*)(Vt + ((size_t)(bh * Dd + d)) * Ss + ch * 128 + sg * 8) = u;
    }
}

// ---------- vpart (fallback mode): partial V sums over 256-row chunks ----------
__global__ __launch_bounds__(256) void vpart_kernel(const float* __restrict__ V,
                                                    float* __restrict__ part) {
    int blk = blockIdx.x, bh = blk >> 3, ch = blk & 7;
    int tid = threadIdx.x, d4 = tid & 31, rg = tid >> 5;
    const fvec4* p = (const fvec4*)(V + ((size_t)bh * Ss + ch * 256) * Dd) + d4;
    fvec4 s = {0.f, 0.f, 0.f, 0.f};
    for (int rr = 0; rr < 32; ++rr) s += p[(size_t)(rg * 32 + rr) * 32];
    __shared__ fvec4 red[256];
    red[tid] = s;
    __syncthreads();
    for (int off = 128; off >= 32; off >>= 1) {
        if (tid < off) red[tid] += red[tid + off];
        __syncthreads();
    }
    if (tid < 32) ((fvec4*)(part + (size_t)blk * Dd))[tid] = red[tid];
}

// ---------- combine partials -> vmean ----------
__global__ __launch_bounds__(128) void vcomb_kernel(const float* __restrict__ part,
                                                    float* __restrict__ vm, int nch) {
    int bh = blockIdx.x, d = threadIdx.x;
    float s = 0.f;
    for (int c = 0; c < nch; ++c) s += part[(size_t)(bh * nch + c) * Dd + d];
    vm[bh * Dd + d] = s * (1.0f / 2048.0f);
}

// ---------- flash attention. MODE 0: gload_lds from pre-converted bf16 (dbuf).
// ----------                  MODE 1: in-kernel cvt staging (fallback). ----------
template<int MODE>
__global__ __launch_bounds__(256, 2) void attn_kernel(
    const float* __restrict__ Qg, const float* __restrict__ Kg,
    const float* __restrict__ Vg, const short* __restrict__ Kbf,
    const short* __restrict__ Vtb, const int* __restrict__ slen,
    const float* __restrict__ vmean, float* __restrict__ Og)
{
    __shared__ __align__(16) short Ks[2][KVB * Dd];    // MODE1 uses [0] only
    __shared__ __align__(16) short Vt[2][Dd * KVB];
    __shared__ __align__(16) short Ps[NW * 32 * KVB];

    const int bid = blockIdx.x;
    const int qslot = bid >> 6, r = bid & 63;
    const int qt = 15 - qslot;                         // longest q-tiles first
    const int b  = (r >> 3) & 3;                       // every batch on every XCD
    const int h  = (r & 7) | ((r >> 5) << 3);
    const int bh = b * 16 + h;                         // (b,h)'s 16 q-tiles share XCD
    const int len = slen[b];
    const int q0 = qt * QBLK;
    const int tid = threadIdx.x;

    if (q0 >= len) {                                   // fully-invalid: rows = mean(V)
        const fvec4* vm4 = (const fvec4*)(vmean + bh * Dd);
        fvec4 val = vm4[tid & 31];
        float* ob = Og + ((size_t)bh * Ss + q0) * Dd;
        int r0 = tid >> 5;
        #pragma unroll
        for (int i = 0; i < 16; ++i)
            ((fvec4*)(ob + (size_t)(r0 + 8 * i) * Dd))[tid & 31] = val;
        return;
    }

    const int w = tid >> 6, lane = tid & 63;
    const int g = lane >> 4, qc = lane & 15;
    const int qw0 = q0 + w * 32;
    const bool wave_active = (qw0 < len);

    const int kv_end   = min(q0 + QBLK, len);
    const int kv_end_w = min(qw0 + 32, kv_end);
    const int nt = (kv_end + KVB - 1) >> 6;

    // per-lane DMA constants (MODE 0): 16B-granule swizzle baked into global src
    int CK[4], CV[4];
    const char* KbhB = (const char*)Kbf + (size_t)bh * Ss * 256;
    const char* VbhB = (const char*)Vtb + (size_t)bh * Dd * (Ss * 2);
    if constexpr (MODE == 0) {
        #pragma unroll
        for (int i = 0; i < 4; ++i) {
            int krow = w * 16 + i * 4 + (lane >> 4);
            int jK = lane & 15;
            int jKs = (jK & 8) | ((jK & 7) ^ (krow & 7));
            CK[i] = krow * 256 + jKs * 16;
            int d = w * 32 + i * 8 + (lane >> 3);
            int jV = lane & 7;
            CV[i] = d * 4096 + (jV ^ (d & 7)) * 16;
        }
    }

    #define GISSUE(tile_, bf_) do {                                                    \
        size_t kb_ = (size_t)(tile_) * (KVB * 256);                                    \
        size_t vb_ = (size_t)(tile_) * (KVB * 2);                                      \
        _Pragma("unroll")                                                              \
        for (int i_ = 0; i_ < 4; ++i_)                                                 \
            gld16(KbhB + kb_ + CK[i_], (char*)Ks[bf_] + w * 4096 + i_ * 1024);         \
        _Pragma("unroll")                                                              \
        for (int i_ = 0; i_ < 4; ++i_)                                                 \
            gld16(VbhB + vb_ + CV[i_], (char*)Vt[bf_] + w * 4096 + i_ * 1024);         \
    } while (0)

    #define STAGE_CVT(kv0_) do {                                                       \
        const fvec4* sk_ = (const fvec4*)(Kg + ((size_t)bh * Ss + (kv0_)) * Dd);       \
        _Pragma("unroll")                                                              \
        for (int i_ = 0; i_ < 8; ++i_) {                                               \
            int f_ = tid + 256 * i_;                                                   \
            int kr_ = f_ >> 5, d4_ = f_ & 31;                                          \
            fvec4 v_ = sk_[(size_t)kr_ * 32 + d4_];                                    \
            u32x2 pr_; pr_[0] = pk2(v_[0], v_[1]); pr_[1] = pk2(v_[2], v_[3]);         \
            int j_ = d4_ >> 1;                                                         \
            int js_ = (j_ & 8) | ((j_ & 7) ^ (kr_ & 7));                               \
            *(u32x2*)((char*)Ks[0] + kr_ * 256 + js_ * 16 + (d4_ & 1) * 8) = pr_;      \
        }                                                                              \
        const float* sv_ = Vg + ((size_t)bh * Ss + (kv0_)) * Dd;                       \
        _Pragma("unroll")                                                              \
        for (int i_ = 0; i_ < 2; ++i_) {                                               \
            int idx_ = tid + 256 * i_;                                                 \
            int dt4_ = idx_ & 31, kt4_ = idx_ >> 5;                                    \
            fvec4 vv_[4];                                                              \
            _Pragma("unroll")                                                          \
            for (int jj_ = 0; jj_ < 4; ++jj_)                                          \
                vv_[jj_] = ((const fvec4*)(sv_ + (size_t)(kt4_ * 4 + jj_) * Dd))[dt4_];\
            _Pragma("unroll")                                                          \
            for (int jj_ = 0; jj_ < 4; ++jj_) {                                        \
                int d_ = dt4_ * 4 + jj_;                                               \
                u32x2 pr_;                                                             \
                pr_[0] = pk2(vv_[0][jj_], vv_[1][jj_]);                                \
                pr_[1] = pk2(vv_[2][jj_], vv_[3][jj_]);                                \
                int bo_ = d_ * 128 + ((kt4_ >> 1) ^ (d_ & 7)) * 16 + (kt4_ & 1) * 8;   \
                *(u32x2*)((char*)Vt[0] + bo_) = pr_;                                   \
            }                                                                          \
        }                                                                              \
    } while (0)

    if constexpr (MODE == 0) GISSUE(0, 0);             // tile 0 DMA flies under Q load

    const float SC = 0.12752870368768582f;             // log2(e)/sqrt(128)
    bf16x8 qf[2][4];
    #pragma unroll
    for (int t2 = 0; t2 < 2; ++t2) {
        const float* qrow = Qg + ((size_t)bh * Ss + (qw0 + 16 * t2 + qc)) * Dd;
        #pragma unroll
        for (int kc = 0; kc < 4; ++kc) {
            const fvec4* p = (const fvec4*)(qrow + kc * 32 + g * 8);
            fvec4 a = p[0], bv = p[1];
            unsigned* fu = (unsigned*)&qf[t2][kc];
            fu[0] = pk2(a[0] * SC, a[1] * SC);
            fu[1] = pk2(a[2] * SC, a[3] * SC);
            fu[2] = pk2(bv[0] * SC, bv[1] * SC);
            fu[3] = pk2(bv[2] * SC, bv[3] * SC);
        }
    }

    if constexpr (MODE == 0) {
        asm volatile("s_waitcnt vmcnt(0)" ::: "memory");
        __syncthreads();
    }

    f32x4 o[2][8];
    #pragma unroll
    for (int t2 = 0; t2 < 2; ++t2)
        #pragma unroll
        for (int dt = 0; dt < 8; ++dt) o[t2][dt] = (f32x4){0.f, 0.f, 0.f, 0.f};
    float m_[2]   = {-3e38f, -3e38f};
    float lsum[2] = {0.f, 0.f};

    char* PsB = (char*)Ps + w * 4096;

    for (int t = 0; t < nt; ++t) {
        const int kv0 = t * KVB;
        const int cur = (MODE == 0) ? (t & 1) : 0;
        const bool pre = (t + 1 < nt);
        const bool active = wave_active && (kv0 < kv_end_w);

        if constexpr (MODE == 0) {
            if (pre) GISSUE(t + 1, (t & 1) ^ 1);       // DMA under this tile's compute
        } else {
            __syncthreads();
            STAGE_CVT(kv0);
            __syncthreads();
        }

        if (active) {
            const char* KsB = (const char*)Ks[cur];
            const char* VtB = (const char*)Vt[cur];
            f32x4 sa[2][4];
            #pragma unroll
            for (int t2 = 0; t2 < 2; ++t2)
                #pragma unroll
                for (int mt = 0; mt < 4; ++mt) sa[t2][mt] = (f32x4){0.f, 0.f, 0.f, 0.f};
            __builtin_amdgcn_s_setprio(1);
            #pragma unroll
            for (int mt = 0; mt < 4; ++mt) {
                int row = mt * 16 + qc;
                bf16x8 kf[4];
                #pragma unroll
                for (int kc = 0; kc < 4; ++kc) {
                    int jb = kc * 4 + g;
                    int js = (jb & 8) | ((jb & 7) ^ (row & 7));
                    kf[kc] = *(const bf16x8*)(KsB + row * 256 + js * 16);
                }
                #pragma unroll
                for (int t2 = 0; t2 < 2; ++t2)
                    #pragma unroll
                    for (int kc = 0; kc < 4; ++kc)
                        sa[t2][mt] = __builtin_amdgcn_mfma_f32_16x16x32_bf16(
                            kf[kc], qf[t2][kc], sa[t2][mt], 0, 0, 0);
            }
            __builtin_amdgcn_s_setprio(0);

            // ---- mask + online softmax (defer-max) ----
            #pragma unroll
            for (int t2 = 0; t2 < 2; ++t2) {
                const int qrow = qw0 + 16 * t2 + qc;
                const bool full = (kv0 + KVB - 1) <= (qw0 + 16 * t2);
                if (!full) {
                    #pragma unroll
                    for (int mt = 0; mt < 4; ++mt)
                        #pragma unroll
                        for (int rr = 0; rr < 4; ++rr) {
                            int kk = kv0 + mt * 16 + g * 4 + rr;
                            if (kk > qrow) sa[t2][mt][rr] = -3e38f;
                        }
                }
                float tm = sa[t2][0][0];
                #pragma unroll
                for (int mt = 0; mt < 4; ++mt)
                    #pragma unroll
                    for (int rr = 0; rr < 4; ++rr) tm = fmaxf(tm, sa[t2][mt][rr]);
                tm = fmaxf(tm, __shfl_xor(tm, 16));
                tm = fmaxf(tm, __shfl_xor(tm, 32));
                if (__any(tm > m_[t2] + 8.0f)) {
                    float mnew = fmaxf(m_[t2], tm);
                    float al = exp2f(m_[t2] - mnew);
                    m_[t2] = mnew;
                    lsum[t2] *= al;
                    #pragma unroll
                    for (int rr = 0; rr < 4; ++rr) {
                        float alr = __shfl(al, g * 4 + rr);
                        #pragma unroll
                        for (int dt = 0; dt < 8; ++dt) o[t2][dt][rr] *= alr;
                    }
                }
                float mref = m_[t2];
                float ls = 0.f;
                int prow = t2 * 16 + qc;
                int pswz = (prow & 7) << 4;
                #pragma unroll
                for (int mt = 0; mt < 4; ++mt) {
                    f32x4 p;
                    #pragma unroll
                    for (int rr = 0; rr < 4; ++rr)
                        p[rr] = exp2f(sa[t2][mt][rr] - mref);
                    ls += (p[0] + p[1]) + (p[2] + p[3]);
                    u32x2 pw;
                    pw[0] = pk2(p[0], p[1]);
                    pw[1] = pk2(p[2], p[3]);
                    *(u32x2*)(PsB + ((prow * 128 + mt * 32 + g * 8) ^ pswz)) = pw;
                }
                lsum[t2] += ls;
            }

            // ---- PV ----
            bf16x8 ap[2][2];
            #pragma unroll
            for (int t2 = 0; t2 < 2; ++t2) {
                int prow = t2 * 16 + qc;
                int pswz = (prow & 7) << 4;
                #pragma unroll
                for (int c = 0; c < 2; ++c)
                    ap[t2][c] = *(const bf16x8*)(PsB + ((prow * 128 + c * 64 + g * 16) ^ pswz));
            }
            __builtin_amdgcn_s_setprio(1);
            #pragma unroll
            for (int dt = 0; dt < 8; ++dt) {
                int d = dt * 16 + qc;
                #pragma unroll
                for (int c = 0; c < 2; ++c) {
                    int js = (c * 4 + g) ^ (d & 7);
                    bf16x8 bfv = *(const bf16x8*)(VtB + d * 128 + js * 16);
                    #pragma unroll
                    for (int t2 = 0; t2 < 2; ++t2)
                        o[t2][dt] = __builtin_amdgcn_mfma_f32_16x16x32_bf16(
                            ap[t2][c], bfv, o[t2][dt], 0, 0, 0);
                }
            }
            __builtin_amdgcn_s_setprio(0);
        }

        if constexpr (MODE == 0) {
            if (pre) {
                asm volatile("s_waitcnt vmcnt(0)" ::: "memory");
                __syncthreads();                       // next buffer fully DMA'd
            }
        }
    }

    // ---- epilogue ----
    float inv_[2][4];
    #pragma unroll
    for (int t2 = 0; t2 < 2; ++t2) {
        float L = lsum[t2];
        L += __shfl_xor(L, 16);
        L += __shfl_xor(L, 32);
        #pragma unroll
        for (int rr = 0; rr < 4; ++rr) {
            float Lr = __shfl(L, g * 4 + rr);
            inv_[t2][rr] = 1.0f / Lr;
        }
    }
    bool needvm = (qw0 + 32 > len);
    float vmv[8];
    #pragma unroll
    for (int dt = 0; dt < 8; ++dt)
        vmv[dt] = needvm ? vmean[bh * Dd + dt * 16 + qc] : 0.f;
    #pragma unroll
    for (int t2 = 0; t2 < 2; ++t2)
        #pragma unroll
        for (int rr = 0; rr < 4; ++rr) {
            int rowg = qw0 + t2 * 16 + g * 4 + rr;
            float* orow = Og + ((size_t)bh * Ss + rowg) * Dd + qc;
            #pragma unroll
            for (int dt = 0; dt < 8; ++dt) {
                float val = o[t2][dt][rr] * inv_[t2][rr];
                if (rowg >= len) val = vmv[dt];
                orow[dt * 16] = val;
            }
        }
    #undef GISSUE
    #undef STAGE_CVT
}

extern "C" void kernel_launch(void* const* d_in, const int* in_sizes, int n_in,
                              void* d_out, int out_size, void* d_ws, size_t ws_size,
                              hipStream_t stream) {
    const float* q  = (const float*)d_in[0];
    const float* k  = (const float*)d_in[1];
    const float* v  = (const float*)d_in[2];
    const int*   sl = (const int*)d_in[3];
    float* out = (float*)d_out;

    const size_t nElem = (size_t)Bb * Hh * Ss * Dd;            // 16,777,216
    const size_t need0 = nElem * 2 * 2 + 1024 * Dd * 4 + 64 * Dd * 4;

    if (ws_size >= need0) {
        short* Kbf  = (short*)d_ws;
        short* Vtb  = Kbf + nElem;
        float* part = (float*)(Vtb + nElem);
        float* vm   = part + 1024 * Dd;
        cvtk_kernel<<<dim3(8192), dim3(256), 0, stream>>>(k, Kbf);
        cvtv_kernel<<<dim3(1024), dim3(256), 0, stream>>>(v, Vtb, part);
        vcomb_kernel<<<dim3(Bb * Hh), dim3(128), 0, stream>>>(part, vm, 16);
        attn_kernel<0><<<dim3(1024), dim3(256), 0, stream>>>(q, k, v, Kbf, Vtb, sl, vm, out);
    } else {
        float* part = (float*)d_ws;                            // 512*128 floats
        float* vm   = part + 512 * Dd;
        vpart_kernel<<<dim3(512), dim3(256), 0, stream>>>(v, part);
        vcomb_kernel<<<dim3(Bb * Hh), dim3(128), 0, stream>>>(part, vm, 8);
        attn_kernel<1><<<dim3(1024), dim3(256), 0, stream>>>(q, k, v, (const short*)nullptr,
                                                             (const short*)nullptr, sl, vm, out);
    }
}